// Round 7
// baseline (889.061 us; speedup 1.0000x reference)
//
#include <hip/hip_runtime.h>

#define HIDDEN 2048
#define HEADS 16
#define HDIM 128
#define BQ 8
#define QLEN 1024
#define KVLEN 4096
#define MROWS (BQ * QLEN)  // 8192

typedef __bf16 bf16x8 __attribute__((ext_vector_type(8)));
typedef float f32x4 __attribute__((ext_vector_type(4)));
typedef unsigned short u16;
typedef u16 u16x8 __attribute__((ext_vector_type(8)));
typedef float f32x8v __attribute__((ext_vector_type(8)));

// async global->LDS, 16B per lane; LDS dest = wave-uniform base + lane*16
__device__ __forceinline__ void async_ld16(const void* g, void* l) {
  __builtin_amdgcn_global_load_lds(
      (const __attribute__((address_space(1))) void*)g,
      (__attribute__((address_space(3))) void*)l, 16, 0, 0);
}

// fp32 -> bf16 narrowing copy (native cast = single v_cvt per element)
__global__ void convert_bf16(const float* __restrict__ src, u16* __restrict__ dst,
                             long n) {
  long base = ((long)blockIdx.x * blockDim.x + threadIdx.x) * 8;
  long stride = (long)gridDim.x * blockDim.x * 8;
  for (long i = base; i < n; i += stride) {
    f32x8v s = *(const f32x8v*)(src + i);
    bf16x8 o;
#pragma unroll
    for (int j = 0; j < 8; j++) o[j] = (__bf16)s[j];
    *(bf16x8*)(dst + i) = o;
  }
}

// V fp32 [KVLEN][HIDDEN] -> Vt bf16 [HEADS*HDIM][KVLEN] (per-head transpose),
// fused with bf16 conversion. Done ONCE: V is shared across batch and q-tiles.
__global__ __launch_bounds__(256) void transpose_v(const float* __restrict__ V,
                                                   u16* __restrict__ Vt) {
  __shared__ __bf16 T[128][129];
  const int kv0 = blockIdx.x * 128;
  const int h = blockIdx.y;
  const int tid = threadIdx.x;
#pragma unroll
  for (int p = 0; p < 8; p++) {
    int idx = p * 2048 + tid * 8;
    int r = idx >> 7, c = idx & 127;  // kv-row, d-col
    f32x8v s = *(const f32x8v*)(V + (size_t)(kv0 + r) * HIDDEN + h * HDIM + c);
#pragma unroll
    for (int j = 0; j < 8; j++) T[r][c + j] = (__bf16)s[j];
  }
  __syncthreads();
#pragma unroll
  for (int p = 0; p < 8; p++) {
    int idx = p * 2048 + tid * 8;
    int d = idx >> 7, kv = idx & 127;
    bf16x8 o;
#pragma unroll
    for (int j = 0; j < 8; j++) o[j] = T[kv + j][d];
    *(bf16x8*)(Vt + ((size_t)h * HDIM + d) * KVLEN + kv0 + kv) = o;
  }
}

// C[M][N] = A[M][K] @ Bt[N][K]^T  (bf16 in, fp32 accum; out bf16 or fp32)
// 128x128 tile, 4 waves (2x2), each wave 64x64 = 4x4 frags of 16x16x32 MFMA.
// Round-7: T3 minimum 2-phase pipeline — BK=32 double-buffered LDS, next
// tile's global_load_lds issued BEFORE current tile's ds_read+MFMA, single
// barrier per K-step (its implicit vmcnt(0) drains the prefetch). Load
// latency hides under the 16-MFMA compute phase instead of being exposed.
__global__ __launch_bounds__(256) void gemm_bt(
    const u16* __restrict__ A, const u16* __restrict__ Bt, void* __restrict__ C,
    int M, int N, int K, int outf) {
  __shared__ __align__(16) u16 Asm[2 * 4 * 128 * 8];  // 2 bufs x 8 KB
  __shared__ __align__(16) u16 Bsm[2 * 4 * 128 * 8];
  const int tid = threadIdx.x;
  const int wid = tid >> 6, lane = tid & 63;
  const int quad = lane >> 4, l15 = lane & 15;
  const int wm = wid >> 1, wn = wid & 1;
  // nwg = 1024 (16 x 64), divisible by 8 -> simple XCD swizzle is bijective
  const int lin = blockIdx.y * gridDim.x + blockIdx.x;
  const int cpx = (gridDim.x * gridDim.y) >> 3;
  const int swz = (lin & 7) * cpx + (lin >> 3);
  const int by = swz / gridDim.x;
  const int bx = swz - by * gridDim.x;
  const int row0 = by * 128;
  const int col0 = bx * 128;

  auto stage = [&](int buf, int k0) {
#pragma unroll
    for (int i = 0; i < 4; i++) {
      int seg = wid + 4 * i;          // 0..15
      int isB = seg >> 3;
      int s = seg & 7;
      int q = s >> 1, hv = s & 1;     // k-octet 0..3, m-half
      const u16* gsrc = isB ? Bt : A;
      int grow = (isB ? col0 : row0) + hv * 64 + lane;
      const u16* g = gsrc + (size_t)grow * K + (k0 + q * 8);
      u16* l = (isB ? Bsm : Asm) + buf * 4096 + (q * 128 + hv * 64) * 8;
      async_ld16(g, l);
    }
  };

  f32x4 acc[4][4];
#pragma unroll
  for (int i = 0; i < 4; i++)
#pragma unroll
    for (int j = 0; j < 4; j++) acc[i][j] = (f32x4){0.f, 0.f, 0.f, 0.f};

  stage(0, 0);
  __syncthreads();  // drain: buf0 ready
  int cur = 0;
  for (int k0 = 0; k0 < K; k0 += 32) {
    if (k0 + 32 < K) stage(cur ^ 1, k0 + 32);  // prefetch next tile
    bf16x8 af[4], bfr[4];
#pragma unroll
    for (int mt = 0; mt < 4; mt++)
      af[mt] = *(const bf16x8*)(Asm + cur * 4096 + (quad * 128 + wm * 64 + mt * 16 + l15) * 8);
#pragma unroll
    for (int nt = 0; nt < 4; nt++)
      bfr[nt] = *(const bf16x8*)(Bsm + cur * 4096 + (quad * 128 + wn * 64 + nt * 16 + l15) * 8);
#pragma unroll
    for (int mt = 0; mt < 4; mt++)
#pragma unroll
      for (int nt = 0; nt < 4; nt++)
        acc[mt][nt] = __builtin_amdgcn_mfma_f32_16x16x32_bf16(af[mt], bfr[nt], acc[mt][nt], 0, 0, 0);
    __syncthreads();  // drains prefetch (vmcnt0) + guards cur-buf reuse
    cur ^= 1;
  }

#pragma unroll
  for (int mt = 0; mt < 4; mt++)
#pragma unroll
    for (int r = 0; r < 4; r++) {
      int row = row0 + wm * 64 + mt * 16 + quad * 4 + r;
#pragma unroll
      for (int nt = 0; nt < 4; nt++) {
        int col = col0 + wn * 64 + nt * 16 + l15;
        if (outf) {
          ((float*)C)[(size_t)row * N + col] = acc[mt][nt][r];
        } else {
          ((__bf16*)C)[(size_t)row * N + col] = (__bf16)acc[mt][nt][r];
        }
      }
    }
}

// Flash attention. 512 thr = 8 waves over a 128-q-row tile; wave owns 16 rows.
// Round-7: separate Kb/Vb buffers -> K[t+1] prefetched right after QK^T(t),
// so K-load latency hides under softmax+PV (previously fully exposed between
// two back-to-back barriers). 2 barriers/tile (was 4). Pb shrunk to a
// quarter-tile (wave-private rows, rewritten between PV quarters, no barrier
// needed). LDS = 32K Kb + 32K Vb + 10K Pb = 74 KB -> 2 blocks/CU.
__global__ __launch_bounds__(512, 4) void attn(
    const u16* __restrict__ Q,   // [MROWS][HIDDEN] bf16
    const u16* __restrict__ Kv,  // [KVLEN][HIDDEN] bf16
    const u16* __restrict__ Vt,  // [HEADS*HDIM][KVLEN] bf16 (per-head V^T)
    u16* __restrict__ O) {       // [MROWS][HIDDEN] bf16
  __shared__ __align__(16) u16 Kb[16 * 1024];    // [d-octet 16][kv 128][8d]
  __shared__ __align__(16) u16 Vb[16 * 1024];    // [kv-octet 16][d 128][8kv]
  __shared__ __align__(16) __bf16 Pb[128 * 40];  // [q 128][32 + 8 pad] one kv-quarter
  const int tid = threadIdx.x;
  const int wid = tid >> 6, lane = tid & 63;    // wid 0..7
  const int quad = lane >> 4, l15 = lane & 15;
  // XCD swizzle: 128 consecutive swizzled ids = 2 heads -> K+V slice 4MB = one L2
  const int lin = blockIdx.x + (blockIdx.y << 3) + (blockIdx.z << 7);
  const int swz = ((lin & 7) << 7) + (lin >> 3);
  const int h = swz >> 6, b = (swz >> 3) & 7, qt = swz & 7;
  const int qrow0 = b * QLEN + qt * 128;
  const int hcol = h * HDIM;
  const float cexp = 0.08838834764831845f * 1.4426950408889634f;  // SCALE*log2(e)

  auto stageK = [&](int kv0) {
#pragma unroll
    for (int i = 0; i < 4; i++) {
      int seg = wid + 8 * i;        // 0..31
      int ch = seg >> 1, sh = seg & 1;   // d-octet, kv-half
      int kvr = kv0 + sh * 64 + lane;
      async_ld16(Kv + (size_t)kvr * HIDDEN + hcol + ch * 8,
                 Kb + (ch * 128 + sh * 64) * 8);
    }
  };
  auto stageV = [&](int kv0) {
#pragma unroll
    for (int i = 0; i < 4; i++) {
      int seg = wid + 8 * i;             // 0..31
      int ch = seg >> 1, dh = seg & 1;   // kv-octet, d-half
      int d = dh * 64 + lane;
      async_ld16(Vt + ((size_t)hcol + d) * KVLEN + kv0 + ch * 8,
                 Vb + (ch * 128 + dh * 64) * 8);
    }
  };

  bf16x8 qf[4];
#pragma unroll
  for (int ks = 0; ks < 4; ks++) {
    int row = qrow0 + wid * 16 + l15;
    qf[ks] = *(const bf16x8*)(Q + (size_t)row * HIDDEN + hcol + ks * 32 + quad * 8);
  }

  f32x4 o[8];
#pragma unroll
  for (int dt = 0; dt < 8; dt++) o[dt] = (f32x4){0.f, 0.f, 0.f, 0.f};
  float mrun[4], lrun[4];
#pragma unroll
  for (int r = 0; r < 4; r++) { mrun[r] = -INFINITY; lrun[r] = 0.f; }

  stageK(0);
  __syncthreads();  // prologue drain: K[0] ready

  for (int t = 0; t < KVLEN / 128; t++) {
    const int kv0 = t << 7;

    // --- QK^T from Kb (K[t] ready) ---
    f32x4 sc[8];
#pragma unroll
    for (int nt = 0; nt < 8; nt++) sc[nt] = (f32x4){0.f, 0.f, 0.f, 0.f};
    __builtin_amdgcn_s_setprio(1);
#pragma unroll
    for (int ks = 0; ks < 4; ks++) {
#pragma unroll
      for (int hf = 0; hf < 2; hf++) {   // 4-reg batches: limit transient VGPRs
        bf16x8 kf[4];
#pragma unroll
        for (int j = 0; j < 4; j++)
          kf[j] = *(const bf16x8*)(Kb + ((ks * 4 + quad) * 128 + (hf * 4 + j) * 16 + l15) * 8);
#pragma unroll
        for (int j = 0; j < 4; j++)
          sc[hf * 4 + j] = __builtin_amdgcn_mfma_f32_16x16x32_bf16(qf[ks], kf[j], sc[hf * 4 + j], 0, 0, 0);
      }
    }
    __builtin_amdgcn_s_setprio(0);
    __syncthreads();  // B2: all QK^T(t) reads done (and all PV(t-1) reads done)

    // Prefetch: V[t] into Vb, K[t+1] into Kb. Both drain at B1; latency
    // hides under softmax (V) and softmax+PV (K).
    stageV(kv0);
    if (t + 1 < KVLEN / 128) stageK(kv0 + 128);

    // --- online softmax with defer-max (T13, THR=8 in raw-score units) ---
    float mx[4];
#pragma unroll
    for (int r = 0; r < 4; r++) {
      float m = sc[0][r];
#pragma unroll
      for (int nt = 1; nt < 8; nt++) m = fmaxf(m, sc[nt][r]);
#pragma unroll
      for (int off = 1; off < 16; off <<= 1) m = fmaxf(m, __shfl_xor(m, off, 64));
      mx[r] = m;
    }
    float gmax = fmaxf(fmaxf(mx[0] - mrun[0], mx[1] - mrun[1]),
                       fmaxf(mx[2] - mrun[2], mx[3] - mrun[3]));
    if (__any(gmax > 8.f)) {   // wave-uniform branch
#pragma unroll
      for (int r = 0; r < 4; r++) {
        float mn = fmaxf(mrun[r], mx[r]);
        float al = __builtin_amdgcn_exp2f((mrun[r] - mn) * cexp);
        mrun[r] = mn;
        lrun[r] *= al;
#pragma unroll
        for (int dt = 0; dt < 8; dt++) o[dt][r] *= al;
      }
    }
#pragma unroll
    for (int r = 0; r < 4; r++) {
      float mc = mrun[r] * cexp;
      float ps = 0.f;
#pragma unroll
      for (int nt = 0; nt < 8; nt++) {
        float p = __builtin_amdgcn_exp2f(sc[nt][r] * cexp - mc);
        sc[nt][r] = p;
        ps += p;
      }
#pragma unroll
      for (int off = 1; off < 16; off <<= 1) ps += __shfl_xor(ps, off, 64);
      lrun[r] += ps;
    }

    // write P kv-quarter 0 (cols 0..31) while V loads are still in flight
#pragma unroll
    for (int nt = 0; nt < 2; nt++)
#pragma unroll
      for (int r = 0; r < 4; r++)
        Pb[(wid * 16 + quad * 4 + r) * 40 + nt * 16 + l15] = (__bf16)sc[nt][r];

    __syncthreads();  // B1: drains vmcnt -> V[t] (and K[t+1]) ready

    // --- PV in 4 kv-quarters; Pb rows are wave-private, rewritten between
    // quarters with per-wave in-order DS (no barrier needed) ---
    __builtin_amdgcn_s_setprio(1);
#pragma unroll
    for (int qq = 0; qq < 4; qq++) {
      bf16x8 pf = *(const bf16x8*)(Pb + (wid * 16 + l15) * 40 + quad * 8);
#pragma unroll
      for (int hf = 0; hf < 2; hf++) {
        bf16x8 vf[4];
#pragma unroll
        for (int j = 0; j < 4; j++)
          vf[j] = *(const bf16x8*)(Vb + ((qq * 4 + quad) * 128 + (hf * 4 + j) * 16 + l15) * 8);
#pragma unroll
        for (int j = 0; j < 4; j++)
          o[hf * 4 + j] = __builtin_amdgcn_mfma_f32_16x16x32_bf16(pf, vf[j], o[hf * 4 + j], 0, 0, 0);
      }
      if (qq < 3) {
#pragma unroll
        for (int nt = 0; nt < 2; nt++)
#pragma unroll
          for (int r = 0; r < 4; r++)
            Pb[(wid * 16 + quad * 4 + r) * 40 + nt * 16 + l15] = (__bf16)sc[2 * (qq + 1) + nt][r];
      }
    }
    __builtin_amdgcn_s_setprio(0);
  }

#pragma unroll
  for (int r = 0; r < 4; r++) {
    float inv = 1.0f / lrun[r];
    int row = qrow0 + wid * 16 + quad * 4 + r;
#pragma unroll
    for (int dt = 0; dt < 8; dt++) {
      int col = hcol + dt * 16 + l15;
      ((__bf16*)O)[(size_t)row * HIDDEN + col] = (__bf16)(o[dt][r] * inv);
    }
  }
}

extern "C" void kernel_launch(void* const* d_in, const int* in_sizes, int n_in,
                              void* d_out, int out_size, void* d_ws, size_t ws_size,
                              hipStream_t stream) {
  const float* query = (const float*)d_in[0];
  const float* kv_k  = (const float*)d_in[1];
  const float* kv_v  = (const float*)d_in[2];
  const float* Wq    = (const float*)d_in[3];
  const float* Wo    = (const float*)d_in[4];
  float* out = (float*)d_out;

  const long NQ = (long)MROWS * HIDDEN;   // 16.78M
  const long NK = (long)KVLEN * HIDDEN;   // 8.39M
  const long NW = (long)HIDDEN * HIDDEN;  // 4.19M

  dim3 blk(256);

  // ws (u16): [convQ NQ][convK NK][Vt NK][convWq NW][convWo NW][Qws NQ]; Ows aliases convQ.
  u16* convQ  = (u16*)d_ws;
  u16* convK  = convQ + NQ;
  u16* Vtb    = convK + NK;
  u16* convWq = Vtb + NK;
  u16* convWo = convWq + NW;
  u16* Qws    = convWo + NW;
  u16* Ows    = convQ;  // convQ dead after gemm1

  convert_bf16<<<dim3((NQ / 8 + 255) / 256), blk, 0, stream>>>(query, convQ,  NQ);
  convert_bf16<<<dim3((NK / 8 + 255) / 256), blk, 0, stream>>>(kv_k,  convK,  NK);
  transpose_v<<<dim3(KVLEN / 128, HEADS), blk, 0, stream>>>(kv_v, Vtb);
  convert_bf16<<<dim3((NW / 8 + 255) / 256), blk, 0, stream>>>(Wq,    convWq, NW);
  convert_bf16<<<dim3((NW / 8 + 255) / 256), blk, 0, stream>>>(Wo,    convWo, NW);

  gemm_bt<<<dim3(HIDDEN / 128, MROWS / 128), blk, 0, stream>>>(convQ, convWq, Qws, MROWS, HIDDEN, HIDDEN, 0);
  attn<<<dim3(QLEN / 128, HEADS, BQ), dim3(512), 0, stream>>>(Qws, convK, Vtb, Ows);
  gemm_bt<<<dim3(HIDDEN / 128, MROWS / 128), blk, 0, stream>>>(Ows, convWo, out, MROWS, HIDDEN, HIDDEN, 1);
}